// Round 5
// baseline (155.813 us; speedup 1.0000x reference)
//
#include <hip/hip_runtime.h>

// YOLO loss, S=14, B=2, C=20, N_EL=30, batch=4096, 16 boxes/row.
// SINGLE compute dispatch (plus a 4-byte memset of d_out):
//   one block per 4096-float4 chunk (exactly 1470 blocks at batch=4096):
//   a) rebuild winner map for the <=4 batch rows overlapping the chunk in LDS
//      (atomicMax of (k<<8)|hot == last-wins scatter semantics);
//   b) stream the chunk as nontemporal coalesced float4 (read-once, 96MB > L2),
//      branchless mask-based per-channel terms (noobj conf ch4/9, class 10..29);
//   c) contain + 5*loc for rows STARTING in this chunk (exact dedupe);
//   d) block shfl-reduce -> one float atomicAdd into out[0].

#define SGRID 14
#define CELLS 196
#define NEL 30
#define NBOX 16
#define PRED_PER_BATCH 5880
#define VEC_PER_ROW 1470               // 5880/4
#define STREAM_ITERS 16
#define STREAM_TPB 256
#define STREAM_CHUNK (STREAM_ITERS * STREAM_TPB)   // 4096 float4
#define WIN_TILE (4 * CELLS + 4)       // 4 rows + straddle pad

typedef float v4f __attribute__((ext_vector_type(4)));

__global__ __launch_bounds__(256) void yolo_fused_kernel(
    const v4f*    __restrict__ pred4,
    const float4* __restrict__ boxes,
    const int*    __restrict__ classes,
    float* __restrict__ out,
    int nvec, int nrows)
{
    __shared__ int   s_win[WIN_TILE];
    __shared__ float s_w4[4];

    const int tid = threadIdx.x;
    const int v0  = blockIdx.x * STREAM_CHUNK;
    const int r0  = v0 / VEC_PER_ROW;          // first batch row overlapping chunk
    const float cellw = (float)(1.0 / 14.0);   // match jnp: divide by float32(1/14)

    // ---- a) clear + build winner tile for rows r0..r0+3 ----
    #pragma unroll
    for (int i = 0; i < (WIN_TILE + STREAM_TPB - 1) / STREAM_TPB; ++i) {
        int idx = tid + i * STREAM_TPB;
        if (idx < WIN_TILE) s_win[idx] = -1;
    }
    __syncthreads();
    if (tid < 4 * NBOX) {
        int rr = tid >> 4, row = r0 + rr, k = tid & 15;
        if (row < nrows) {
            float4 bx = boxes[row * NBOX + k];
            float cx = (bx.x + bx.z) * 0.5f, cy = (bx.y + bx.w) * 0.5f;
            float fx = cx / cellw, fy = cy / cellw;
            float fi = fminf(fmaxf(ceilf(fx) - 1.0f, 0.0f), 13.0f);
            float fj = fminf(fmaxf(ceilf(fy) - 1.0f, 0.0f), 13.0f);
            int cell = (int)fj * SGRID + (int)fi;
            int hot  = 9 + classes[row * NBOX + k];  // faithful off-by-one
            atomicMax(&s_win[rr * CELLS + cell], (k << 8) | hot);
        }
    }
    __syncthreads();

    // ---- b) stream chunk: 16 nontemporal float4 (uniform tail branch) ----
    const int cellbase = r0 * CELLS;
    float loss = 0.0f;
    const bool full = (v0 + STREAM_CHUNK) <= nvec;
    #pragma unroll
    for (int i = 0; i < STREAM_ITERS; ++i) {
        int e = v0 + tid + i * STREAM_TPB;
        if (full || e < nvec) {
            v4f v = __builtin_nontemporal_load(pred4 + e);
            int g    = e * 4;
            int cell = (int)((unsigned)g / 30u);   // magic-mul div
            int c0   = g - cell * 30;
            int lc   = cell - cellbase;
            int m0 = s_win[lc];
            int m1 = s_win[lc + 1];                // straddle pad covers lc+1
            #pragma unroll
            for (int j = 0; j < 4; ++j) {
                int cj = c0 + j;
                bool str = cj >= 30;
                int cc = str ? cj - 30 : cj;
                int m  = str ? m1 : m0;
                // active-channel bitmask: noobj -> conf ch 4,9 @0.5 ; obj -> ch 10..29 @1
                unsigned amask = (m < 0) ? 0x210u : 0x3FFFFC00u;
                float scale    = (m < 0) ? 0.5f : 1.0f;
                float wgt = ((amask >> cc) & 1u) ? scale : 0.0f;
                float tt  = (cc == (m & 0xFF)) ? 1.0f : 0.0f;  // m<0 -> 255, no hit
                float d = v[j] - tt;
                loss += wgt * d * d;
            }
        }
    }

    // ---- c) obj loss for rows starting in this chunk (dedupe across blocks) ----
    if (tid < 4 * NBOX) {
        int rr = tid >> 4, row = r0 + rr, k = tid & 15;
        int rstart = row * VEC_PER_ROW;
        if (row < nrows && rstart >= v0 && rstart < v0 + STREAM_CHUNK) {
            float4 bx = boxes[row * NBOX + k];
            float w = bx.z - bx.x, h = bx.w - bx.y;
            float cx = (bx.x + bx.z) * 0.5f, cy = (bx.y + bx.w) * 0.5f;
            float fx = cx / cellw, fy = cy / cellw;
            float fi = fminf(fmaxf(ceilf(fx) - 1.0f, 0.0f), 13.0f);
            float fj = fminf(fmaxf(ceilf(fy) - 1.0f, 0.0f), 13.0f);
            float dx = fx - fi, dy = fy - fj;
            int cell = (int)fj * SGRID + (int)fi;
            int wv = s_win[rr * CELLS + cell];
            if ((wv >> 8) == k) {                  // this box won its cell
                const float* p = (const float*)pred4 + (size_t)(row * CELLS + cell) * NEL;
                float a[10];
                #pragma unroll
                for (int j = 0; j < 5; ++j) {      // 8B-aligned float2 loads
                    float2 v = *(const float2*)(p + 2 * j);
                    a[2 * j] = v.x;  a[2 * j + 1] = v.y;
                }
                // corner-format "IoU" of (dx,dy,w,h) rows verbatim (per reference)
                float area_t = (w - dx) * (h - dy);
                float iou[2];
                #pragma unroll
                for (int i = 0; i < 2; ++i) {
                    const float* q = a + i * 5;
                    float ltx = fmaxf(q[0], dx), lty = fmaxf(q[1], dy);
                    float rbx = fminf(q[2], w),  rby = fminf(q[3], h);
                    float wi = fmaxf(rbx - ltx, 0.0f);
                    float hi = fmaxf(rby - lty, 0.0f);
                    float inter  = wi * hi;
                    float area_a = (q[2] - q[0]) * (q[3] - q[1]);
                    float uni    = area_a + area_t - inter;
                    iou[i] = inter / ((uni == 0.0f) ? 1.0f : uni);
                }
                int r = (iou[1] > iou[0]) ? 1 : 0; // argmax tie -> 0
                const float* q = a + r * 5;
                float dc = q[4] - 1.0f;            // contain
                loss += dc * dc;
                float lx = q[0] - dx, ly = q[1] - dy;  // 5 * loc
                float lw = sqrtf(q[2]) - sqrtf(w);
                float lh = sqrtf(q[3]) - sqrtf(h);
                loss += 5.0f * (lx * lx + ly * ly + lw * lw + lh * lh);
            }
        }
    }

    // ---- d) block reduce -> one atomicAdd per block (1470 total, spread) ----
    #pragma unroll
    for (int off = 32; off > 0; off >>= 1)
        loss += __shfl_down(loss, off, 64);
    if ((tid & 63) == 0) s_w4[tid >> 6] = loss;
    __syncthreads();
    if (tid == 0)
        atomicAdd(out, s_w4[0] + s_w4[1] + s_w4[2] + s_w4[3]);
}

extern "C" void kernel_launch(void* const* d_in, const int* in_sizes, int n_in,
                              void* d_out, int out_size, void* d_ws, size_t ws_size,
                              hipStream_t stream) {
    const float* pred    = (const float*)d_in[0];
    const float* boxes   = (const float*)d_in[1];
    const int*   classes = (const int*)d_in[2];
    float* out = (float*)d_out;

    const int nrows = in_sizes[0] / PRED_PER_BATCH;        // 4096
    const int nvec  = nrows * PRED_PER_BATCH / 4;          // 6021120 float4
    const int sblocks = (nvec + STREAM_CHUNK - 1) / STREAM_CHUNK;  // 1470 (exact)

    hipMemsetAsync(d_out, 0, sizeof(float) * out_size, stream);
    yolo_fused_kernel<<<dim3(sblocks), dim3(STREAM_TPB), 0, stream>>>(
        (const v4f*)pred, (const float4*)boxes, classes, out, nvec, nrows);
}

// Round 6
// 145.307 us; speedup vs baseline: 1.0723x; 1.0723x over previous
//
#include <hip/hip_runtime.h>

// YOLO loss, S=14, B=2, C=20, N_EL=30, batch=4096, 16 boxes/row.
// 2 dispatches (fused stream + 1-block reduce). R4 skeleton + deep-MLP loads:
//   one block per 3072-float4 chunk (1960 blocks, EXACT at batch=4096):
//   a) prefetch this block's 4 rows of boxes/classes into registers, then
//      clear+build the LDS winner map (atomicMax (k<<8)|hot == last-wins);
//   b) full blocks: issue ALL 12 coalesced float4 loads unconditionally into
//      a register array (12 outstanding loads/thread), then branchless
//      per-channel terms (noobj conf ch4/9 @0.5, class ch10..29 @1) with
//      incremental (cell,c0) tracking; rare tail block takes a guarded loop;
//   c) contain + 5*loc for rows STARTING in this chunk (exact dedupe);
//   d) block shfl-reduce -> plain partial store; 1-block reduce -> out[0].

#define SGRID 14
#define CELLS 196
#define NEL 30
#define NBOX 16
#define PRED_PER_BATCH 5880
#define VEC_PER_ROW 1470               // 5880/4
#define STREAM_ITERS 12
#define STREAM_TPB 256
#define STREAM_CHUNK (STREAM_ITERS * STREAM_TPB)   // 3072 float4
#define WIN_TILE (4 * CELLS + 4)       // 4 rows + straddle pad

typedef float v4f __attribute__((ext_vector_type(4)));

__device__ __forceinline__ float channel_terms(v4f v, int c0, int m0, int m1) {
    float loss = 0.0f;
    #pragma unroll
    for (int j = 0; j < 4; ++j) {
        int cj = c0 + j;
        bool str = cj >= 30;
        int cc = str ? cj - 30 : cj;
        int m  = str ? m1 : m0;
        // noobj -> conf ch 4,9 @0.5 ; obj -> class ch 10..29 @1
        unsigned amask = (m < 0) ? 0x210u : 0x3FFFFC00u;
        float scale    = (m < 0) ? 0.5f : 1.0f;
        float wgt = ((amask >> cc) & 1u) ? scale : 0.0f;
        float tt  = (cc == (m & 0xFF)) ? 1.0f : 0.0f;  // m<0 -> 255, no hit
        float d = v[j] - tt;
        loss = fmaf(wgt * d, d, loss);
    }
    return loss;
}

__global__ __launch_bounds__(256) void yolo_fused_kernel(
    const v4f*    __restrict__ pred4,
    const float4* __restrict__ boxes,
    const int*    __restrict__ classes,
    float* __restrict__ partials,
    int nvec, int nrows)
{
    __shared__ int   s_win[WIN_TILE];
    __shared__ float s_w4[4];

    const int tid = threadIdx.x;
    const int v0  = blockIdx.x * STREAM_CHUNK;
    const int r0  = v0 / VEC_PER_ROW;          // first batch row overlapping chunk
    const float cellw = (float)(1.0 / 14.0);   // match jnp: divide by float32(1/14)

    // ---- a) prefetch boxes/classes (overlaps LDS clear), build winner tile ----
    float4 bx; int cls = 0; bool has_box = false;
    int rr = tid >> 4, row = r0 + rr, k = tid & 15;
    if (tid < 4 * NBOX && row < nrows) {
        bx  = boxes[row * NBOX + k];           // issued before the LDS clear
        cls = classes[row * NBOX + k];
        has_box = true;
    }
    #pragma unroll
    for (int i = 0; i < (WIN_TILE + STREAM_TPB - 1) / STREAM_TPB; ++i) {
        int idx = tid + i * STREAM_TPB;
        if (idx < WIN_TILE) s_win[idx] = -1;
    }
    __syncthreads();
    float dx, dy, bw, bh; int cell = 0;
    if (has_box) {
        bw = bx.z - bx.x;  bh = bx.w - bx.y;
        float cx = (bx.x + bx.z) * 0.5f, cy = (bx.y + bx.w) * 0.5f;
        float fx = cx / cellw, fy = cy / cellw;
        float fi = fminf(fmaxf(ceilf(fx) - 1.0f, 0.0f), 13.0f);
        float fj = fminf(fmaxf(ceilf(fy) - 1.0f, 0.0f), 13.0f);
        dx = fx - fi;  dy = fy - fj;
        cell = (int)fj * SGRID + (int)fi;
        atomicMax(&s_win[rr * CELLS + cell], (k << 8) | (9 + cls));  // off-by-one faithful
    }
    __syncthreads();

    // ---- b) stream chunk ----
    const int cellbase = r0 * CELLS;
    float loss = 0.0f;
    if (v0 + STREAM_CHUNK <= nvec) {
        // full block: all 12 loads in flight before any consumption
        v4f vv[STREAM_ITERS];
        #pragma unroll
        for (int i = 0; i < STREAM_ITERS; ++i)
            vv[i] = pred4[v0 + tid + i * STREAM_TPB];
        int g0 = (v0 + tid) * 4;
        int c  = (int)((unsigned)g0 / 30u);    // one magic div
        int c0 = g0 - c * 30;                  // even, 0..28
        int lc = c - cellbase;
        #pragma unroll
        for (int i = 0; i < STREAM_ITERS; ++i) {
            loss += channel_terms(vv[i], c0, s_win[lc], s_win[lc + 1]);
            // advance by 1024 floats: +34 cells, +4 channels (wrap at 30)
            lc += 34;  c0 += 4;
            if (c0 >= 30) { c0 -= 30; lc += 1; }
        }
    } else {
        // rare tail block: guarded per-element path
        for (int i = 0; i < STREAM_ITERS; ++i) {
            int e = v0 + tid + i * STREAM_TPB;
            if (e < nvec) {
                v4f v = pred4[e];
                int g = e * 4;
                int c = (int)((unsigned)g / 30u);
                loss += channel_terms(v, g - c * 30, s_win[c - cellbase],
                                      s_win[c - cellbase + 1]);
            }
        }
    }

    // ---- c) obj loss for rows starting in this chunk (dedupe across blocks) ----
    if (has_box) {
        int rstart = row * VEC_PER_ROW;
        if (rstart >= v0 && rstart < v0 + STREAM_CHUNK) {
            int wv = s_win[rr * CELLS + cell];
            if ((wv >> 8) == k) {                  // this box won its cell
                const float* p = (const float*)pred4 + (size_t)(row * CELLS + cell) * NEL;
                float a[10];
                #pragma unroll
                for (int j = 0; j < 5; ++j) {      // 8B-aligned float2 loads
                    float2 v = *(const float2*)(p + 2 * j);
                    a[2 * j] = v.x;  a[2 * j + 1] = v.y;
                }
                // corner-format "IoU" of (dx,dy,w,h) rows verbatim (per reference)
                float area_t = (bw - dx) * (bh - dy);
                float iou[2];
                #pragma unroll
                for (int i = 0; i < 2; ++i) {
                    const float* q = a + i * 5;
                    float ltx = fmaxf(q[0], dx), lty = fmaxf(q[1], dy);
                    float rbx = fminf(q[2], bw), rby = fminf(q[3], bh);
                    float wi = fmaxf(rbx - ltx, 0.0f);
                    float hi = fmaxf(rby - lty, 0.0f);
                    float inter  = wi * hi;
                    float area_a = (q[2] - q[0]) * (q[3] - q[1]);
                    float uni    = area_a + area_t - inter;
                    iou[i] = inter / ((uni == 0.0f) ? 1.0f : uni);
                }
                int r = (iou[1] > iou[0]) ? 1 : 0; // argmax tie -> 0
                const float* q = a + r * 5;
                float dc = q[4] - 1.0f;            // contain
                loss += dc * dc;
                float lx = q[0] - dx, ly = q[1] - dy;  // 5 * loc
                float lw = sqrtf(q[2]) - sqrtf(bw);
                float lh = sqrtf(q[3]) - sqrtf(bh);
                loss += 5.0f * (lx * lx + ly * ly + lw * lw + lh * lh);
            }
        }
    }

    // ---- d) block reduce -> plain partial store ----
    #pragma unroll
    for (int off = 32; off > 0; off >>= 1)
        loss += __shfl_down(loss, off, 64);
    if ((tid & 63) == 0) s_w4[tid >> 6] = loss;
    __syncthreads();
    if (tid == 0)
        partials[blockIdx.x] = s_w4[0] + s_w4[1] + s_w4[2] + s_w4[3];
}

__global__ __launch_bounds__(256) void final_reduce_kernel(
    const float* __restrict__ partials, float* __restrict__ out, int n)
{
    float s = 0.0f;
    for (int i = threadIdx.x; i < n; i += 256) s += partials[i];
    #pragma unroll
    for (int off = 32; off > 0; off >>= 1)
        s += __shfl_down(s, off, 64);
    __shared__ float w4[4];
    if ((threadIdx.x & 63) == 0) w4[threadIdx.x >> 6] = s;
    __syncthreads();
    if (threadIdx.x == 0) out[0] = w4[0] + w4[1] + w4[2] + w4[3];
}

extern "C" void kernel_launch(void* const* d_in, const int* in_sizes, int n_in,
                              void* d_out, int out_size, void* d_ws, size_t ws_size,
                              hipStream_t stream) {
    const float* pred    = (const float*)d_in[0];
    const float* boxes   = (const float*)d_in[1];
    const int*   classes = (const int*)d_in[2];
    float* out = (float*)d_out;

    const int nrows = in_sizes[0] / PRED_PER_BATCH;        // 4096
    const int nvec  = nrows * PRED_PER_BATCH / 4;          // 6021120 float4
    const int sblocks = (nvec + STREAM_CHUNK - 1) / STREAM_CHUNK;  // 1960 (exact)

    float* partials = (float*)d_ws;

    yolo_fused_kernel<<<dim3(sblocks), dim3(STREAM_TPB), 0, stream>>>(
        (const v4f*)pred, (const float4*)boxes, classes, partials, nvec, nrows);
    final_reduce_kernel<<<dim3(1), dim3(256), 0, stream>>>(partials, out, sblocks);
}